// Round 1
// baseline (5744.510 us; speedup 1.0000x reference)
//
#include <hip/hip_runtime.h>
#include <hip/hip_bf16.h>
#include <stdint.h>

// EncoderFLAX: x = emb[inputs]; xW = x@Wi + b; LSTM scan over S with Wh.
// B=256 S=256 V=32000 E=1024 H=1024. Outputs: [B,S,H] fp32, h [B,H], c [B,H].
//
// Plan:
//   prep:  zero c-state + h_bf16[0]; transpose-cast Wi,Wh -> [N,K] bf16
//   x:     gather+cast emb rows -> bf16 [65536,1024]
//   xW:    m97-structure bf16 MFMA GEMM (128x128 tile, BK=32, global_load_lds
//          width 16) -> bf16 [65536,4096], bias added in epilogue
//   scan:  256 sequential kernels; each block = 32 batch rows x 32 h-cols,
//          8 waves (gate g = wid&3, row-half = wid>>2); h staged in LDS with
//          XOR chunk swizzle (both-sides: pre-swizzled global source, swizzled
//          ds_read) to kill the [32][1024] row-major 16-way bank conflict;
//          WhT fragments read direct from (XCD-resident) L2; cell in fp32.
//
// ws layout (bytes):
//   WiT 0..8388608, WhT ..16777216, hb0 ..17301504, hb1 ..17825792,
//   X ..152043520, XW ..688914432   (~657 MiB total)

#define B_ 256
#define S_ 256
#define E_ 1024
#define H_ 1024
#define G_ 4096
#define M_ 65536

typedef float  f32x4  __attribute__((ext_vector_type(4)));
typedef __bf16 bf16x8 __attribute__((ext_vector_type(8)));

#define MFMA16(a, b, c) __builtin_amdgcn_mfma_f32_16x16x32_bf16((a), (b), (c), 0, 0, 0)

__device__ __forceinline__ void gload_lds16(const void* g, void* l) {
  __builtin_amdgcn_global_load_lds(
      (__attribute__((address_space(1))) void*)(g),
      (__attribute__((address_space(3))) void*)(l), 16, 0, 0);
}

__device__ __forceinline__ float sigm(float x) { return 1.f / (1.f + __expf(-x)); }
__device__ __forceinline__ float tanhfast(float x) {
  float e = __expf(-2.f * x);
  return (1.f - e) / (1.f + e);
}

// ---------------------------------------------------------------- zero init
__global__ __launch_bounds__(256) void zero_init(uint4* c16, uint4* h16) {
  int i = blockIdx.x * 256 + threadIdx.x;
  uint4 z; z.x = z.y = z.z = z.w = 0u;
  if (i < 65536) c16[i] = z;            // c state: 262144 f32 = 65536 x 16B
  else if (i < 98304) h16[i - 65536] = z; // hb0: 262144 bf16 = 32768 x 16B
}

// ------------------------------------------------- transpose+cast [1024][4096]
// in [R=1024][C=4096] f32 -> out [C][R] bf16 (so GEMM B-fragments are K-contig)
__global__ __launch_bounds__(256) void transpose_cast(const float* __restrict__ in,
                                                      __bf16* __restrict__ out) {
  __shared__ __bf16 tile[32][33];
  const int c0 = blockIdx.x * 32;
  const int r0 = blockIdx.y * 32;
  const int tx = threadIdx.x & 31, ty = threadIdx.x >> 5;
#pragma unroll
  for (int p = 0; p < 4; ++p) {
    const int rr = ty + p * 8;
    tile[rr][tx] = (__bf16)in[(size_t)(r0 + rr) * G_ + c0 + tx];
  }
  __syncthreads();
#pragma unroll
  for (int p = 0; p < 4; ++p) {
    const int rr = ty + p * 8;
    out[(size_t)(c0 + rr) * E_ + r0 + tx] = tile[tx][rr];
  }
}

// ------------------------------------------------------- embedding gather+cast
union U16b { uint4 v; __bf16 h[8]; };
__global__ __launch_bounds__(256) void gather_cast(const int* __restrict__ idx,
                                                   const float* __restrict__ emb,
                                                   __bf16* __restrict__ X) {
  const size_t gid  = (size_t)blockIdx.x * 256 + threadIdx.x;
  const size_t base = gid * 8;                  // 8 elems/thread
  const int r = (int)(base >> 10);
  const int e = (int)(base & 1023);
  const int row = idx[r];
  const float4* s = (const float4*)(emb + (size_t)row * E_ + e);
  const float4 v0 = s[0], v1 = s[1];
  U16b u;
  u.h[0] = (__bf16)v0.x; u.h[1] = (__bf16)v0.y; u.h[2] = (__bf16)v0.z; u.h[3] = (__bf16)v0.w;
  u.h[4] = (__bf16)v1.x; u.h[5] = (__bf16)v1.y; u.h[6] = (__bf16)v1.z; u.h[7] = (__bf16)v1.w;
  *(uint4*)(X + base) = u.v;
}

// --------------------------------------------------- xW GEMM (m97 structure)
// C[65536,4096] = X[65536,1024] @ WiT^T + bias, bf16 in/out, fp32 accum.
// 128x128 tile, BK=32, 4 waves, global_load_lds width=16, 2-barrier loop.
__global__ __launch_bounds__(256) void gemm_xw(const __bf16* __restrict__ X,
                                               const __bf16* __restrict__ WiT,
                                               const float* __restrict__ bias,
                                               __bf16* __restrict__ XW) {
  __shared__ __bf16 As[128 * 32];
  __shared__ __bf16 Bs[128 * 32];
  const int tid = threadIdx.x;
  const int lane = tid & 63;
  const int wid = tid >> 6;
  const int bn = blockIdx.x & 31;       // 4096/128
  const int bm = blockIdx.x >> 5;       // 65536/128
  const int row0 = bm * 128, col0 = bn * 128;
  const int wr = (wid >> 1) * 64, wc = (wid & 1) * 64;
  const int srow = tid >> 2, schunk = tid & 3;   // staging: 4 lanes/row, 16B each
  const char* gA = (const char*)(X + (size_t)(row0 + srow) * E_) + schunk * 16;
  const char* gB = (const char*)(WiT + (size_t)(col0 + srow) * E_) + schunk * 16;
  char* lA = (char*)As + wid * 1024;
  char* lB = (char*)Bs + wid * 1024;
  const int fr = lane & 15, kb = lane >> 4;

  f32x4 acc[4][4] = {};

  for (int kt = 0; kt < 32; ++kt) {
    gload_lds16(gA + kt * 64,              lA);
    gload_lds16(gA + kt * 64 + 64 * 2048,  lA + 4096);
    gload_lds16(gB + kt * 64,              lB);
    gload_lds16(gB + kt * 64 + 64 * 2048,  lB + 4096);
    __syncthreads();
    bf16x8 a[4], b[4];
#pragma unroll
    for (int m = 0; m < 4; ++m)
      a[m] = *(const bf16x8*)((const char*)As + (wr + m * 16 + fr) * 64 + kb * 16);
#pragma unroll
    for (int n = 0; n < 4; ++n)
      b[n] = *(const bf16x8*)((const char*)Bs + (wc + n * 16 + fr) * 64 + kb * 16);
#pragma unroll
    for (int m = 0; m < 4; ++m)
#pragma unroll
      for (int n = 0; n < 4; ++n)
        acc[m][n] = MFMA16(a[m], b[n], acc[m][n]);
    __syncthreads();
  }

#pragma unroll
  for (int n = 0; n < 4; ++n) {
    const int col = col0 + wc + n * 16 + fr;
    const float bv = bias[col];
#pragma unroll
    for (int m = 0; m < 4; ++m) {
      const int rowb = row0 + wr + m * 16 + kb * 4;
#pragma unroll
      for (int r = 0; r < 4; ++r)
        XW[(size_t)(rowb + r) * G_ + col] = (__bf16)(acc[m][n][r] + bv);
    }
  }
}

// --------------------------------------------------------------- LSTM step t
// grid 256 blocks: block = 32 batch rows x 32 h-cols (all 4 gates).
// blockIdx remap puts all 8 batch-groups of a col-group on the same XCD
// (bid%8 == XCD) so each XCD's 1MB WhT slice stays L2-resident.
__global__ __launch_bounds__(512) void lstm_step(const __bf16* __restrict__ hin,
                                                 __bf16* __restrict__ hout,
                                                 const __bf16* __restrict__ WhT,
                                                 const __bf16* __restrict__ XW,
                                                 float* __restrict__ outp,
                                                 float* __restrict__ cst,
                                                 float* __restrict__ hfin,
                                                 int t) {
  __shared__ __bf16 As[32 * 1024];     // 64 KB, XOR-swizzled 16B chunks
  __shared__ float  zs[4][32][33];     // gate exchange, padded
  const int tid = threadIdx.x;
  const int lane = tid & 63;
  const int wid = tid >> 6;
  const int bid = blockIdx.x;
  const int bg = (bid >> 3) & 7;                 // batch group
  const int cg = (bid & 7) + (bid >> 6) * 8;     // col group (0..31)
  const int b0 = bg * 32;
  const int c0 = cg * 32;

  // Stage h rows [b0,b0+32) -> As. LDS dest is linear (tid*16); the 16B-chunk
  // XOR swizzle is applied to the GLOBAL source address (rule: both-sides).
  {
    const int chunk = tid & 127;      // 16B chunk within 2KB row
    const int rsub = tid >> 7;        // 0..3
#pragma unroll
    for (int cc = 0; cc < 8; ++cc) {
      const int row = cc * 4 + rsub;
      const char* src = (const char*)(hin + (size_t)(b0 + row) * H_) +
                        ((chunk ^ (row & 7)) * 16);
      gload_lds16(src, (char*)As + cc * 8192 + wid * 1024);
    }
  }
  __syncthreads();

  const int g = wid & 3;      // gate (i,f,g,o)
  const int mh = wid >> 2;    // row half (0/1)
  const int fr = lane & 15, kb = lane >> 4;
  const int arow = mh * 16 + fr;
  const __bf16* wb0 = WhT + (size_t)(g * 1024 + c0 + fr) * H_;
  const __bf16* wb1 = WhT + (size_t)(g * 1024 + c0 + 16 + fr) * H_;
  f32x4 acc0 = {0.f, 0.f, 0.f, 0.f}, acc1 = {0.f, 0.f, 0.f, 0.f};
#pragma unroll 4
  for (int kt = 0; kt < 32; ++kt) {
    const int ck = kt * 4 + kb;
    bf16x8 a = *(const bf16x8*)((const char*)As + arow * 2048 +
                                ((ck ^ (arow & 7)) * 16));
    bf16x8 bv0 = *(const bf16x8*)(wb0 + kt * 32 + kb * 8);
    bf16x8 bv1 = *(const bf16x8*)(wb1 + kt * 32 + kb * 8);
    acc0 = MFMA16(a, bv0, acc0);
    acc1 = MFMA16(a, bv1, acc1);
  }
#pragma unroll
  for (int r = 0; r < 4; ++r) {
    zs[g][mh * 16 + kb * 4 + r][fr]      = acc0[r];
    zs[g][mh * 16 + kb * 4 + r][16 + fr] = acc1[r];
  }
  __syncthreads();

  // Cell: 1024 (row,col) elems, 2 per thread, fp32 math.
  const int crow = tid >> 4;
  const int ccolb = (tid & 15) * 2;
  const size_t xwbase = ((size_t)(b0 + crow) * S_ + t) * G_ + c0 + ccolb;
  const size_t sidx = (size_t)(b0 + crow) * H_ + c0 + ccolb;
#pragma unroll
  for (int j = 0; j < 2; ++j) {
    const float zi = zs[0][crow][ccolb + j] + (float)XW[xwbase + j];
    const float zf = zs[1][crow][ccolb + j] + (float)XW[xwbase + 1024 + j];
    const float zg = zs[2][crow][ccolb + j] + (float)XW[xwbase + 2048 + j];
    const float zo = zs[3][crow][ccolb + j] + (float)XW[xwbase + 3072 + j];
    const float iv = sigm(zi), fv = sigm(zf), gv = tanhfast(zg), ov = sigm(zo);
    const float cv = fv * cst[sidx + j] + iv * gv;
    cst[sidx + j] = cv;
    const float hv = ov * tanhfast(cv);
    outp[(size_t)(b0 + crow) * (S_ * H_) + (size_t)t * H_ + c0 + ccolb + j] = hv;
    hout[sidx + j] = (__bf16)hv;
    if (t == S_ - 1) hfin[sidx + j] = hv;
  }
}

// ----------------------------------------------------------------- launcher
extern "C" void kernel_launch(void* const* d_in, const int* in_sizes, int n_in,
                              void* d_out, int out_size, void* d_ws, size_t ws_size,
                              hipStream_t stream) {
  const int*   inp  = (const int*)d_in[0];
  const float* emb  = (const float*)d_in[1];
  const float* Wi   = (const float*)d_in[2];
  const float* Wh   = (const float*)d_in[3];
  const float* bias = (const float*)d_in[4];

  char* ws = (char*)d_ws;
  __bf16* WiT = (__bf16*)(ws);
  __bf16* WhT = (__bf16*)(ws + 8388608);
  __bf16* hb0 = (__bf16*)(ws + 16777216);
  __bf16* hb1 = (__bf16*)(ws + 17301504);
  __bf16* X   = (__bf16*)(ws + 17825792);
  __bf16* XW  = (__bf16*)(ws + 152043520);   // needs ws_size >= ~689 MB

  float* outp = (float*)d_out;
  float* hfin = outp + (size_t)M_ * H_;      // 67,108,864
  float* cst  = hfin + (size_t)B_ * H_;      // +262,144

  zero_init<<<384, 256, 0, stream>>>((uint4*)cst, (uint4*)hb0);
  transpose_cast<<<dim3(128, 32), 256, 0, stream>>>(Wi, WiT);
  transpose_cast<<<dim3(128, 32), 256, 0, stream>>>(Wh, WhT);
  gather_cast<<<32768, 256, 0, stream>>>(inp, emb, X);
  gemm_xw<<<16384, 256, 0, stream>>>(X, WiT, bias, XW);
  for (int t = 0; t < S_; ++t) {
    const __bf16* hi = (t & 1) ? hb1 : hb0;
    __bf16* ho = (t & 1) ? hb0 : hb1;
    lstm_step<<<256, 512, 0, stream>>>(hi, ho, WhT, XW, outp, cst, hfin, t);
  }
}